// Round 8
// baseline (86.603 us; speedup 1.0000x reference)
//
#include <hip/hip_runtime.h>
#include <math.h>

namespace {
constexpr int T_ = 64;
constexpr int D_ = 32;

typedef _Float16 half2 __attribute__((ext_vector_type(2)));
typedef _Float16 half4 __attribute__((ext_vector_type(4)));
typedef _Float16 half8 __attribute__((ext_vector_type(8)));
typedef float f32x4 __attribute__((ext_vector_type(4)));

union H4 { half4 v4; half2 v2[2]; };
union H8 { half8 v8; half2 v2[4]; };

// ---------------------------------------------------------------------------
// Prep (runs once):
//   gis32[nt][mt][lane][4] f32 = gi(q,k)/sqrt(8)*log2e                (16 KB)
//   lb32 [h][nt][mt][lane][4] f32 = rel*gi*log2e                      (64 KB)
//   wfr  [m][h][lane][8] fp16: per-head A/B fragments for QKV proj:
//        val = (l4<8) ? Wm[8*(lane>>4)+j][8h+l4] : 0                  (12 KB)
//        (zero rows 8..15 give the QK zero-guard for free)
//   wo_img[nt][lane][8] fp16 = Wo[8*(lane>>4)+j][l4+16nt]             (2 KB)
// Masked (k>q): gis=0, lb=0 -> logit 0 -> e=1 (ref: mask multiplies logits).
// ---------------------------------------------------------------------------
__global__ __launch_bounds__(256) void gia_prep(
    const float* __restrict__ qw, const float* __restrict__ kw,
    const float* __restrict__ vw, const float* __restrict__ ow,
    const float* __restrict__ rel, const float* __restrict__ lgi,
    float* __restrict__ gis32, float* __restrict__ lb32,
    _Float16* __restrict__ wfr, _Float16* __restrict__ wo_img)
{
    int t = blockIdx.x * 256 + threadIdx.x;
    const float gv = __expf(lgi[0]);
    const float LOG2E = 1.4426950408889634f;
    const float INVS  = 0.35355339059327373f;   // 1/sqrt(8)
    if (t < 1024) {
        int nt = t >> 8, mt = (t >> 6) & 3, lane = t & 63;
        int q  = (lane & 15) + 16 * nt;
        int k0 = 16 * mt + 4 * (lane >> 4);
#pragma unroll
        for (int r = 0; r < 4; ++r) {
            int k = k0 + r;
            float gi = 0.0f;
            if (k <= q) {
                float lag = (float)(q - k);
                float z = (lag - gv) / (0.5f * gv);
                gi = 0.7f * __expf(-0.5f * z * z) + 0.3f * __expf(-0.1f * lag);
            }
            gis32[t * 4 + r] = gi * INVS * LOG2E;
        }
    } else if (t < 5120) {
        int e = t - 1024;
        int h = e >> 10, nt = (e >> 8) & 3, mt = (e >> 6) & 3, lane = e & 63;
        int q  = (lane & 15) + 16 * nt;
        int k0 = 16 * mt + 4 * (lane >> 4);
#pragma unroll
        for (int r = 0; r < 4; ++r) {
            int k = k0 + r;
            float gi = 0.0f;
            if (k <= q) {
                float lag = (float)(q - k);
                float z = (lag - gv) / (0.5f * gv);
                gi = 0.7f * __expf(-0.5f * z * z) + 0.3f * __expf(-0.1f * lag);
            }
            lb32[e * 4 + r] = rel[(h * 64 + q) * 64 + k] * gi * LOG2E;
        }
    } else if (t < 5888) {
        int idx = t - 5120;                 // [3][4][64]
        int m = idx >> 8, lane = idx & 63;
        int h = (idx >> 6) & 3;
        int l4 = lane & 15, gg = lane >> 4;
        const float* wp = (m == 0) ? qw : (m == 1) ? kw : vw;
#pragma unroll
        for (int j = 0; j < 8; ++j) {
            float v = (l4 < 8) ? wp[(8 * gg + j) * 32 + 8 * h + l4] : 0.0f;
            wfr[(size_t)idx * 8 + j] = (_Float16)v;
        }
    } else if (t < 6016) {
        int idx = t - 5888;                 // [2][64]
        int nt = idx >> 6, lane = idx & 63;
        int l4 = lane & 15, gg = lane >> 4;
#pragma unroll
        for (int j = 0; j < 8; ++j)
            wo_img[(size_t)idx * 8 + j] =
                (_Float16)ow[(8 * gg + j) * 32 + l4 + 16 * nt];
    }
}

// ---------------------------------------------------------------------------
// Main: one block per (b,n), 4 waves, TWO barriers, LDS ~10.8 KB.
// P0: coop-coalesced x -> LDS fp16 (one 8KB stage, not 4x redundant global).
// Wave h: xa fragments from LDS -> Q^T/K^T/V proj MFMAs whose C-layouts ARE
// the attention fragments (Q/K/V never touch LDS) -> swapped-QK attention
// (fma+exp2 softmax, ones-column row sums) -> O to LDS -> barrier ->
// o-proj (wave = token-tile) with deferred normalization.
// ---------------------------------------------------------------------------
__global__ __launch_bounds__(256, 8) void gia_main(
    const float* __restrict__ x,
    const float* __restrict__ qb_, const float* __restrict__ kb_,
    const float* __restrict__ vb_, const float* __restrict__ ob_,
    const float* __restrict__ gis32, const float* __restrict__ lb32,
    const _Float16* __restrict__ wfr, const _Float16* __restrict__ wo_img,
    float* __restrict__ out)
{
    __shared__ __align__(16) _Float16 xs[64][40];    // x tile fp16
    __shared__ __align__(16) _Float16 os_[64][40];   // O [token][ch]
    __shared__ _Float16 invS[4][64];                 // row sums (head, q)

    const int tid  = threadIdx.x;
    const int lane = tid & 63;
    const int w    = tid >> 6;        // wave id = head h; token-tile in P4
    const int l4   = lane & 15;
    const int g    = lane >> 4;
    const int bn   = blockIdx.x;
    const int h    = w;

    // ---- hoisted per-head weight fragments + biases (small L2-hot tables) ----
    half8 wq8 = *(const half8*)&wfr[((0 * 4 + h) * 64 + lane) * 8];
    half8 wk8 = *(const half8*)&wfr[((1 * 4 + h) * 64 + lane) * 8];
    half8 wv8 = *(const half8*)&wfr[((2 * 4 + h) * 64 + lane) * 8];
    float bq[4], bk[4];
#pragma unroll
    for (int r = 0; r < 4; ++r) {
        bq[r] = (g < 2) ? qb_[8 * h + 4 * g + r] : 0.0f;   // g>=2: frag rows
        bk[r] = (g < 2) ? kb_[8 * h + 4 * g + r] : 0.0f;   // are zero too
    }
    float bv = (l4 < 8) ? vb_[8 * h + l4] : 0.0f;

    // ---- P0: coop stage x (coalesced float4, fp32->fp16) ----
    {
        const float4* xv = (const float4*)(x + (size_t)bn * 2048);
        float4 a = xv[2 * tid], b = xv[2 * tid + 1];
        int t = tid >> 2, c = (tid & 3) * 8;
        H8 u;
        u.v2[0] = __builtin_bit_cast(half2, __builtin_amdgcn_cvt_pkrtz(a.x, a.y));
        u.v2[1] = __builtin_bit_cast(half2, __builtin_amdgcn_cvt_pkrtz(a.z, a.w));
        u.v2[2] = __builtin_bit_cast(half2, __builtin_amdgcn_cvt_pkrtz(b.x, b.y));
        u.v2[3] = __builtin_bit_cast(half2, __builtin_amdgcn_cvt_pkrtz(b.z, b.w));
        *(half8*)&xs[t][c] = u.v8;
    }
    __syncthreads();

    // ---- xa fragments: A-frag (row=token) AND B-frag (col=token), same bytes ----
    half8 xa[4];
#pragma unroll
    for (int t = 0; t < 4; ++t)
        xa[t] = *(const half8*)&xs[l4 + 16 * t][8 * g];

    // ---- projections: C-layout == next MFMA's fragment layout ----
    half4 kfr[4], qfr[4], vfr[4];
#pragma unroll
    for (int t = 0; t < 4; ++t) {      // K^T: lane=key, regs=ch (QK A-frag)
        f32x4 z = {};
        f32x4 c = __builtin_amdgcn_mfma_f32_16x16x32_f16(wk8, xa[t], z, 0, 0, 0);
        H4 u;
        u.v2[0] = __builtin_bit_cast(half2, __builtin_amdgcn_cvt_pkrtz(c[0] + bk[0], c[1] + bk[1]));
        u.v2[1] = __builtin_bit_cast(half2, __builtin_amdgcn_cvt_pkrtz(c[2] + bk[2], c[3] + bk[3]));
        kfr[t] = u.v4;
    }
#pragma unroll
    for (int t = 0; t < 4; ++t) {      // Q^T: lane=q, regs=ch (QK B-frag)
        f32x4 z = {};
        f32x4 c = __builtin_amdgcn_mfma_f32_16x16x32_f16(wq8, xa[t], z, 0, 0, 0);
        H4 u;
        u.v2[0] = __builtin_bit_cast(half2, __builtin_amdgcn_cvt_pkrtz(c[0] + bq[0], c[1] + bq[1]));
        u.v2[1] = __builtin_bit_cast(half2, __builtin_amdgcn_cvt_pkrtz(c[2] + bq[2], c[3] + bq[3]));
        qfr[t] = u.v4;
    }
#pragma unroll
    for (int t = 0; t < 4; ++t) {      // V: lane=ch, regs=key (PV B-frag)
        f32x4 z = {};
        f32x4 c = __builtin_amdgcn_mfma_f32_16x16x32_f16(xa[t], wv8, z, 0, 0, 0);
        H4 u;
        u.v2[0] = __builtin_bit_cast(half2, __builtin_amdgcn_cvt_pkrtz(c[0] + bv, c[1] + bv));
        u.v2[1] = __builtin_bit_cast(half2, __builtin_amdgcn_cvt_pkrtz(c[2] + bv, c[3] + bv));
        half4 vv = u.v4;
        if (l4 == 8) vv = (half4){(_Float16)1.0f, (_Float16)1.0f,
                                  (_Float16)1.0f, (_Float16)1.0f};  // ones col
        vfr[t] = vv;
    }

    // ---- attention: swapped QK, no-max-sub softmax, deferred norm ----
#pragma unroll
    for (int nt = 0; nt < 4; ++nt) {
        f32x4 s[4];
#pragma unroll
        for (int mt = 0; mt < 4; ++mt) {
            f32x4 z = {};
            // S^T: lane holds S^T[key=4g+r+16mt][q=l4+16nt]
            s[mt] = __builtin_amdgcn_mfma_f32_16x16x16f16(kfr[mt], qfr[nt], z, 0, 0, 0);
        }
        half4 af[4];
#pragma unroll
        for (int mt = 0; mt < 4; ++mt) {
            f32x4 g4  = *(const f32x4*)&gis32[((nt * 4 + mt) * 64 + lane) * 4];
            f32x4 lbv = *(const f32x4*)&lb32[(((h * 4 + nt) * 4 + mt) * 64 + lane) * 4];
            float t0 = fmaf(s[mt][0], g4[0], lbv[0]);
            float t1 = fmaf(s[mt][1], g4[1], lbv[1]);
            float t2 = fmaf(s[mt][2], g4[2], lbv[2]);
            float t3 = fmaf(s[mt][3], g4[3], lbv[3]);
            H4 u;
            u.v2[0] = __builtin_bit_cast(half2, __builtin_amdgcn_cvt_pkrtz(exp2f(t0), exp2f(t1)));
            u.v2[1] = __builtin_bit_cast(half2, __builtin_amdgcn_cvt_pkrtz(exp2f(t2), exp2f(t3)));
            af[mt] = u.v4;
        }
        f32x4 oacc = {};
#pragma unroll
        for (int ks = 0; ks < 4; ++ks)
            oacc = __builtin_amdgcn_mfma_f32_16x16x16f16(af[ks], vfr[ks], oacc, 0, 0, 0);
        if (l4 < 8) {
#pragma unroll
            for (int r = 0; r < 4; ++r)
                os_[4 * g + r + 16 * nt][8 * h + l4] = (_Float16)oacc[r];
        } else if (l4 == 8) {
#pragma unroll
            for (int r = 0; r < 4; ++r)
                invS[h][4 * g + r + 16 * nt] = (_Float16)oacc[r];
        }
    }
    __syncthreads();

    // ---- P4: o-proj (16x16x32), wave = token rows 16w..16w+15 ----
    {
        half8 wo0 = *(const half8*)&wo_img[(0 * 64 + lane) * 8];
        half8 wo1 = *(const half8*)&wo_img[(1 * 64 + lane) * 8];
        float obv0 = ob_[l4], obv1 = ob_[l4 + 16];

        half8 oa = *(const half8*)&os_[16 * w + l4][8 * g];  // head g, token 16w+l4
        float iv = 1.0f / (float)invS[g][16 * w + l4];
        _Float16 hv = (_Float16)iv;
        oa *= (half8){hv, hv, hv, hv, hv, hv, hv, hv};

        float* yout = out + (size_t)bn * 2048;
        f32x4 z0 = {}, z1 = {};
        f32x4 y0 = __builtin_amdgcn_mfma_f32_16x16x32_f16(oa, wo0, z0, 0, 0, 0);
        f32x4 y1 = __builtin_amdgcn_mfma_f32_16x16x32_f16(oa, wo1, z1, 0, 0, 0);
#pragma unroll
        for (int r = 0; r < 4; ++r) {
            yout[(16 * w + 4 * g + r) * 32 + l4]      = y0[r] + obv0;
            yout[(16 * w + 4 * g + r) * 32 + l4 + 16] = y1[r] + obv1;
        }
    }
}

} // namespace

extern "C" void kernel_launch(void* const* d_in, const int* in_sizes, int n_in,
                              void* d_out, int out_size, void* d_ws, size_t ws_size,
                              hipStream_t stream)
{
    const float* x   = (const float*)d_in[0];
    const float* qw  = (const float*)d_in[1];
    const float* qb  = (const float*)d_in[2];
    const float* kw  = (const float*)d_in[3];
    const float* kb  = (const float*)d_in[4];
    const float* vw  = (const float*)d_in[5];
    const float* vb  = (const float*)d_in[6];
    const float* ow  = (const float*)d_in[7];
    const float* ob  = (const float*)d_in[8];
    const float* rel = (const float*)d_in[9];
    const float* lgi = (const float*)d_in[10];
    float* outp = (float*)d_out;

    float*    gis32  = (float*)d_ws;                      // 16384 B
    float*    lb32   = (float*)((char*)d_ws + 16384);     // 65536 B
    _Float16* wfr    = (_Float16*)((char*)d_ws + 81920);  // 12288 B
    _Float16* wo_img = (_Float16*)((char*)d_ws + 94208);  //  2048 B

    const int bn_count = in_sizes[0] / (T_ * D_);         // 8000

    gia_prep<<<dim3(24), dim3(256), 0, stream>>>(qw, kw, vw, ow, rel, lgi,
                                                 gis32, lb32, wfr, wo_img);
    gia_main<<<dim3(bn_count), dim3(256), 0, stream>>>(
        x, qb, kb, vb, ob, gis32, lb32, wfr, wo_img, outp);
}

// Round 9
// 65.470 us; speedup vs baseline: 1.3228x; 1.3228x over previous
//
#include <hip/hip_runtime.h>
#include <math.h>

namespace {
constexpr int T_ = 64;
constexpr int D_ = 32;

typedef _Float16 half2 __attribute__((ext_vector_type(2)));
typedef _Float16 half4 __attribute__((ext_vector_type(4)));
typedef _Float16 half8 __attribute__((ext_vector_type(8)));
typedef float f32x4 __attribute__((ext_vector_type(4)));

union H4 { half4 v4; half2 v2[2]; };
union H8 { half8 v8; half2 v2[4]; };

// ---------------------------------------------------------------------------
// Prep (runs once):
//   gis32[nt][mt][lane][4] f32 = gi(q,k)/sqrt(8)*log2e                (16 KB)
//   lb32 [h][nt][mt][lane][4] f32 = rel*gi*log2e                      (64 KB)
//   wfr  [m][h][lane][8] fp16: per-head A/B fragments for QKV proj:
//        val = (l4<8) ? Wm[8*(lane>>4)+j][8h+l4] : 0                  (12 KB)
//        (zero rows 8..15 give the QK zero-guard for free)
//   wo_img[nt][lane][8] fp16 = Wo[8*(lane>>4)+j][l4+16nt]             (2 KB)
// Masked (k>q): gis=0, lb=0 -> logit 0 -> e=1 (ref: mask multiplies logits).
// ---------------------------------------------------------------------------
__global__ __launch_bounds__(256) void gia_prep(
    const float* __restrict__ qw, const float* __restrict__ kw,
    const float* __restrict__ vw, const float* __restrict__ ow,
    const float* __restrict__ rel, const float* __restrict__ lgi,
    float* __restrict__ gis32, float* __restrict__ lb32,
    _Float16* __restrict__ wfr, _Float16* __restrict__ wo_img)
{
    int t = blockIdx.x * 256 + threadIdx.x;
    const float gv = __expf(lgi[0]);
    const float LOG2E = 1.4426950408889634f;
    const float INVS  = 0.35355339059327373f;   // 1/sqrt(8)
    if (t < 1024) {
        int nt = t >> 8, mt = (t >> 6) & 3, lane = t & 63;
        int q  = (lane & 15) + 16 * nt;
        int k0 = 16 * mt + 4 * (lane >> 4);
#pragma unroll
        for (int r = 0; r < 4; ++r) {
            int k = k0 + r;
            float gi = 0.0f;
            if (k <= q) {
                float lag = (float)(q - k);
                float z = (lag - gv) / (0.5f * gv);
                gi = 0.7f * __expf(-0.5f * z * z) + 0.3f * __expf(-0.1f * lag);
            }
            gis32[t * 4 + r] = gi * INVS * LOG2E;
        }
    } else if (t < 5120) {
        int e = t - 1024;
        int h = e >> 10, nt = (e >> 8) & 3, mt = (e >> 6) & 3, lane = e & 63;
        int q  = (lane & 15) + 16 * nt;
        int k0 = 16 * mt + 4 * (lane >> 4);
#pragma unroll
        for (int r = 0; r < 4; ++r) {
            int k = k0 + r;
            float gi = 0.0f;
            if (k <= q) {
                float lag = (float)(q - k);
                float z = (lag - gv) / (0.5f * gv);
                gi = 0.7f * __expf(-0.5f * z * z) + 0.3f * __expf(-0.1f * lag);
            }
            lb32[e * 4 + r] = rel[(h * 64 + q) * 64 + k] * gi * LOG2E;
        }
    } else if (t < 5888) {
        int idx = t - 5120;                 // [3][4][64]
        int m = idx >> 8, lane = idx & 63;
        int h = (idx >> 6) & 3;
        int l4 = lane & 15, gg = lane >> 4;
        const float* wp = (m == 0) ? qw : (m == 1) ? kw : vw;
#pragma unroll
        for (int j = 0; j < 8; ++j) {
            float v = (l4 < 8) ? wp[(8 * gg + j) * 32 + 8 * h + l4] : 0.0f;
            wfr[(size_t)idx * 8 + j] = (_Float16)v;
        }
    } else if (t < 6016) {
        int idx = t - 5888;                 // [2][64]
        int nt = idx >> 6, lane = idx & 63;
        int l4 = lane & 15, gg = lane >> 4;
#pragma unroll
        for (int j = 0; j < 8; ++j)
            wo_img[(size_t)idx * 8 + j] =
                (_Float16)ow[(8 * gg + j) * 32 + l4 + 16 * nt];
    }
}

// ---------------------------------------------------------------------------
// Main: one block per (b,n), 4 waves, TWO barriers, LDS ~10.8 KB.
// Identical to R8 EXCEPT __launch_bounds__(256, 4): R8's (256,8) capped
// VGPRs at 64 -> massive scratch spill (WRITE_SIZE 160MB vs 64MB output).
// 4 waves/SIMD keeps the ~100-VGPR working set in registers.
// ---------------------------------------------------------------------------
__global__ __launch_bounds__(256, 4) void gia_main(
    const float* __restrict__ x,
    const float* __restrict__ qb_, const float* __restrict__ kb_,
    const float* __restrict__ vb_, const float* __restrict__ ob_,
    const float* __restrict__ gis32, const float* __restrict__ lb32,
    const _Float16* __restrict__ wfr, const _Float16* __restrict__ wo_img,
    float* __restrict__ out)
{
    __shared__ __align__(16) _Float16 xs[64][40];    // x tile fp16
    __shared__ __align__(16) _Float16 os_[64][40];   // O [token][ch]
    __shared__ _Float16 invS[4][64];                 // row sums (head, q)

    const int tid  = threadIdx.x;
    const int lane = tid & 63;
    const int w    = tid >> 6;        // wave id = head h; token-tile in P4
    const int l4   = lane & 15;
    const int g    = lane >> 4;
    const int bn   = blockIdx.x;
    const int h    = w;

    // ---- hoisted per-head weight fragments + biases (small L2-hot tables) ----
    half8 wq8 = *(const half8*)&wfr[((0 * 4 + h) * 64 + lane) * 8];
    half8 wk8 = *(const half8*)&wfr[((1 * 4 + h) * 64 + lane) * 8];
    half8 wv8 = *(const half8*)&wfr[((2 * 4 + h) * 64 + lane) * 8];
    float bq[4], bk[4];
#pragma unroll
    for (int r = 0; r < 4; ++r) {
        bq[r] = (g < 2) ? qb_[8 * h + 4 * g + r] : 0.0f;   // g>=2: frag rows
        bk[r] = (g < 2) ? kb_[8 * h + 4 * g + r] : 0.0f;   // are zero too
    }
    float bv = (l4 < 8) ? vb_[8 * h + l4] : 0.0f;

    // ---- P0: coop stage x (coalesced float4, fp32->fp16) ----
    {
        const float4* xv = (const float4*)(x + (size_t)bn * 2048);
        float4 a = xv[2 * tid], b = xv[2 * tid + 1];
        int t = tid >> 2, c = (tid & 3) * 8;
        H8 u;
        u.v2[0] = __builtin_bit_cast(half2, __builtin_amdgcn_cvt_pkrtz(a.x, a.y));
        u.v2[1] = __builtin_bit_cast(half2, __builtin_amdgcn_cvt_pkrtz(a.z, a.w));
        u.v2[2] = __builtin_bit_cast(half2, __builtin_amdgcn_cvt_pkrtz(b.x, b.y));
        u.v2[3] = __builtin_bit_cast(half2, __builtin_amdgcn_cvt_pkrtz(b.z, b.w));
        *(half8*)&xs[t][c] = u.v8;
    }
    __syncthreads();

    // ---- xa fragments: A-frag (row=token) AND B-frag (col=token), same bytes ----
    half8 xa[4];
#pragma unroll
    for (int t = 0; t < 4; ++t)
        xa[t] = *(const half8*)&xs[l4 + 16 * t][8 * g];

    // ---- projections: C-layout == next MFMA's fragment layout ----
    half4 kfr[4], qfr[4], vfr[4];
#pragma unroll
    for (int t = 0; t < 4; ++t) {      // K^T: lane=key, regs=ch (QK A-frag)
        f32x4 z = {};
        f32x4 c = __builtin_amdgcn_mfma_f32_16x16x32_f16(wk8, xa[t], z, 0, 0, 0);
        H4 u;
        u.v2[0] = __builtin_bit_cast(half2, __builtin_amdgcn_cvt_pkrtz(c[0] + bk[0], c[1] + bk[1]));
        u.v2[1] = __builtin_bit_cast(half2, __builtin_amdgcn_cvt_pkrtz(c[2] + bk[2], c[3] + bk[3]));
        kfr[t] = u.v4;
    }
#pragma unroll
    for (int t = 0; t < 4; ++t) {      // Q^T: lane=q, regs=ch (QK B-frag)
        f32x4 z = {};
        f32x4 c = __builtin_amdgcn_mfma_f32_16x16x32_f16(wq8, xa[t], z, 0, 0, 0);
        H4 u;
        u.v2[0] = __builtin_bit_cast(half2, __builtin_amdgcn_cvt_pkrtz(c[0] + bq[0], c[1] + bq[1]));
        u.v2[1] = __builtin_bit_cast(half2, __builtin_amdgcn_cvt_pkrtz(c[2] + bq[2], c[3] + bq[3]));
        qfr[t] = u.v4;
    }
#pragma unroll
    for (int t = 0; t < 4; ++t) {      // V: lane=ch, regs=key (PV B-frag)
        f32x4 z = {};
        f32x4 c = __builtin_amdgcn_mfma_f32_16x16x32_f16(xa[t], wv8, z, 0, 0, 0);
        H4 u;
        u.v2[0] = __builtin_bit_cast(half2, __builtin_amdgcn_cvt_pkrtz(c[0] + bv, c[1] + bv));
        u.v2[1] = __builtin_bit_cast(half2, __builtin_amdgcn_cvt_pkrtz(c[2] + bv, c[3] + bv));
        half4 vv = u.v4;
        if (l4 == 8) vv = (half4){(_Float16)1.0f, (_Float16)1.0f,
                                  (_Float16)1.0f, (_Float16)1.0f};  // ones col
        vfr[t] = vv;
    }

    // ---- attention: swapped QK, no-max-sub softmax, deferred norm ----
#pragma unroll
    for (int nt = 0; nt < 4; ++nt) {
        f32x4 s[4];
#pragma unroll
        for (int mt = 0; mt < 4; ++mt) {
            f32x4 z = {};
            // S^T: lane holds S^T[key=4g+r+16mt][q=l4+16nt]
            s[mt] = __builtin_amdgcn_mfma_f32_16x16x16f16(kfr[mt], qfr[nt], z, 0, 0, 0);
        }
        half4 af[4];
#pragma unroll
        for (int mt = 0; mt < 4; ++mt) {
            f32x4 g4  = *(const f32x4*)&gis32[((nt * 4 + mt) * 64 + lane) * 4];
            f32x4 lbv = *(const f32x4*)&lb32[(((h * 4 + nt) * 4 + mt) * 64 + lane) * 4];
            float t0 = fmaf(s[mt][0], g4[0], lbv[0]);
            float t1 = fmaf(s[mt][1], g4[1], lbv[1]);
            float t2 = fmaf(s[mt][2], g4[2], lbv[2]);
            float t3 = fmaf(s[mt][3], g4[3], lbv[3]);
            H4 u;
            u.v2[0] = __builtin_bit_cast(half2, __builtin_amdgcn_cvt_pkrtz(exp2f(t0), exp2f(t1)));
            u.v2[1] = __builtin_bit_cast(half2, __builtin_amdgcn_cvt_pkrtz(exp2f(t2), exp2f(t3)));
            af[mt] = u.v4;
        }
        f32x4 oacc = {};
#pragma unroll
        for (int ks = 0; ks < 4; ++ks)
            oacc = __builtin_amdgcn_mfma_f32_16x16x16f16(af[ks], vfr[ks], oacc, 0, 0, 0);
        if (l4 < 8) {
#pragma unroll
            for (int r = 0; r < 4; ++r)
                os_[4 * g + r + 16 * nt][8 * h + l4] = (_Float16)oacc[r];
        } else if (l4 == 8) {
#pragma unroll
            for (int r = 0; r < 4; ++r)
                invS[h][4 * g + r + 16 * nt] = (_Float16)oacc[r];
        }
    }
    __syncthreads();

    // ---- P4: o-proj (16x16x32), wave = token rows 16w..16w+15 ----
    {
        half8 wo0 = *(const half8*)&wo_img[(0 * 64 + lane) * 8];
        half8 wo1 = *(const half8*)&wo_img[(1 * 64 + lane) * 8];
        float obv0 = ob_[l4], obv1 = ob_[l4 + 16];

        half8 oa = *(const half8*)&os_[16 * w + l4][8 * g];  // head g, token 16w+l4
        float iv = 1.0f / (float)invS[g][16 * w + l4];
        _Float16 hv = (_Float16)iv;
        oa *= (half8){hv, hv, hv, hv, hv, hv, hv, hv};

        float* yout = out + (size_t)bn * 2048;
        f32x4 z0 = {}, z1 = {};
        f32x4 y0 = __builtin_amdgcn_mfma_f32_16x16x32_f16(oa, wo0, z0, 0, 0, 0);
        f32x4 y1 = __builtin_amdgcn_mfma_f32_16x16x32_f16(oa, wo1, z1, 0, 0, 0);
#pragma unroll
        for (int r = 0; r < 4; ++r) {
            yout[(16 * w + 4 * g + r) * 32 + l4]      = y0[r] + obv0;
            yout[(16 * w + 4 * g + r) * 32 + l4 + 16] = y1[r] + obv1;
        }
    }
}

} // namespace

extern "C" void kernel_launch(void* const* d_in, const int* in_sizes, int n_in,
                              void* d_out, int out_size, void* d_ws, size_t ws_size,
                              hipStream_t stream)
{
    const float* x   = (const float*)d_in[0];
    const float* qw  = (const float*)d_in[1];
    const float* qb  = (const float*)d_in[2];
    const float* kw  = (const float*)d_in[3];
    const float* kb  = (const float*)d_in[4];
    const float* vw  = (const float*)d_in[5];
    const float* vb  = (const float*)d_in[6];
    const float* ow  = (const float*)d_in[7];
    const float* ob  = (const float*)d_in[8];
    const float* rel = (const float*)d_in[9];
    const float* lgi = (const float*)d_in[10];
    float* outp = (float*)d_out;

    float*    gis32  = (float*)d_ws;                      // 16384 B
    float*    lb32   = (float*)((char*)d_ws + 16384);     // 65536 B
    _Float16* wfr    = (_Float16*)((char*)d_ws + 81920);  // 12288 B
    _Float16* wo_img = (_Float16*)((char*)d_ws + 94208);  //  2048 B

    const int bn_count = in_sizes[0] / (T_ * D_);         // 8000

    gia_prep<<<dim3(24), dim3(256), 0, stream>>>(qw, kw, vw, ow, rel, lgi,
                                                 gis32, lb32, wfr, wo_img);
    gia_main<<<dim3(bn_count), dim3(256), 0, stream>>>(
        x, qb, kb, vb, ob, gis32, lb32, wfr, wo_img, outp);
}